// Round 12
// baseline (164.481 us; speedup 1.0000x reference)
//
#include <hip/hip_runtime.h>
#include <hip/hip_bf16.h>
#include <math.h>

// Problem constants
#define BB 2
#define NN 4096
#define CC 256
#define HH 8
#define MM 48
#define TT 10000
#define LL 256
#define CHDIM 32
#define HIDD 512
#define ROWS (BB*NN)   // 8192

typedef __attribute__((ext_vector_type(8))) short bf16x8;
typedef __attribute__((ext_vector_type(4))) float f32x4;
typedef __attribute__((address_space(1))) const unsigned int gas_t;
typedef __attribute__((address_space(3))) unsigned int las_t;

static __device__ __forceinline__ short f2bf(float x) {
    __hip_bfloat16 h = __float2bfloat16(x);
    return *reinterpret_cast<short*>(&h);
}
static __device__ __forceinline__ float bf2f(short s) {
    unsigned int u = ((unsigned int)(unsigned short)s) << 16;
    union { unsigned int u; float f; } c; c.u = u;
    return c.f;
}

// ---------------- weight transpose descriptors ----------------
struct WtDesc { const float* src; __hip_bfloat16* dst; int K; int N; int tile0; float scl; };
struct WtArgs { WtDesc d[9]; };

// ---------------- merged prep: weight transpose | pe_table | bias | memory->bf16 ----------------
__global__ __launch_bounds__(256) void prep_all_kernel(WtArgs a,
    const float* __restrict__ pre, const float* __restrict__ Wpe,
    const float* __restrict__ bpe, float* __restrict__ pet,
    const float* __restrict__ bq, const float* __restrict__ bkv,
    const float* __restrict__ xbk, const float* __restrict__ xbv,
    const float* __restrict__ xbq, float scale,
    float* __restrict__ bqkv, float* __restrict__ xbkv, float* __restrict__ xbqS,
    const float* __restrict__ memory, __hip_bfloat16* __restrict__ memBf) {
    __shared__ float tile[32][33];
    int bid = blockIdx.x, tid = threadIdx.x;
    if (bid < 768) {
        int mi = 0;
        #pragma unroll
        for (int i = 1; i < 9; ++i) if (bid >= a.d[i].tile0) mi = i;
        WtDesc dsc = a.d[mi];
        int t = bid - dsc.tile0;
        int tiles_n = dsc.N >> 5;
        int k0 = (t / tiles_n) * 32, n0 = (t % tiles_n) * 32;
        int tx = tid & 31, ty = tid >> 5;   // 32x8
        #pragma unroll
        for (int i = 0; i < 32; i += 8)
            tile[ty + i][tx] = dsc.src[(size_t)(k0 + ty + i) * dsc.N + n0 + tx];
        __syncthreads();
        #pragma unroll
        for (int i = 0; i < 32; i += 8)
            dsc.dst[(size_t)(n0 + ty + i) * dsc.K + k0 + tx] = __float2bfloat16(tile[tx][ty + i] * dsc.scl);
        return;
    }
    bid -= 768;
    if (bid < 313) {
        int i = bid * 256 + tid;
        if (i >= TT * HH) return;
        int t = i / HH, h = i % HH;
        float s = bpe[h];
        #pragma unroll
        for (int j = 0; j < 5; ++j) s += pre[t * 5 + j] * Wpe[j * HH + h];
        pet[i] = s;
    } else if (bid < 319) {
        int i = (bid - 313) * 256 + tid;
        if (i < 256) bqkv[i] = bq[i] * scale;
        else if (i < 768) bqkv[i] = bkv[i - 256];
        else if (i < 1024) xbkv[i - 768] = xbk[i - 768];
        else if (i < 1280) xbkv[256 + i - 1024] = xbv[i - 1024];
        else if (i < 1536) xbqS[i - 1280] = xbq[i - 1280] * scale;
    } else {
        int i = (bid - 319) * 256 + tid;
        if (i < 131072) memBf[i] = __float2bfloat16(memory[i]);
    }
}

// ---------------- LayerNorm v2: wave-per-row, float4, no LDS/sync ----------------
__global__ __launch_bounds__(256) void ln_kernel(const float* __restrict__ in,
                                                 const float* __restrict__ g,
                                                 const float* __restrict__ b,
                                                 __hip_bfloat16* __restrict__ out) {
    int wave = threadIdx.x >> 6, lane = threadIdx.x & 63;
    int row = blockIdx.x * 4 + wave;
    float4 v = ((const float4*)(in + (size_t)row * CC))[lane];
    float s = (v.x + v.y) + (v.z + v.w);
    #pragma unroll
    for (int off = 32; off; off >>= 1) s += __shfl_xor(s, off, 64);
    float mu = s * (1.0f / 256.0f);
    float dx = v.x - mu, dy = v.y - mu, dz = v.z - mu, dw = v.w - mu;
    float s2 = (dx * dx + dy * dy) + (dz * dz + dw * dw);
    #pragma unroll
    for (int off = 32; off; off >>= 1) s2 += __shfl_xor(s2, off, 64);
    float rs = rsqrtf(s2 * (1.0f / 256.0f) + 1e-5f);
    float4 g4 = ((const float4*)g)[lane];
    float4 b4 = ((const float4*)b)[lane];
    ushort4 o4;
    o4.x = (unsigned short)f2bf(dx * rs * g4.x + b4.x);
    o4.y = (unsigned short)f2bf(dy * rs * g4.y + b4.y);
    o4.z = (unsigned short)f2bf(dz * rs * g4.z + b4.z);
    o4.w = (unsigned short)f2bf(dw * rs * g4.w + b4.w);
    *(ushort4*)((unsigned short*)out + (size_t)row * CC + lane * 4) = o4;
}

// ---------------- MFMA bf16 GEMM body: global_load_lds staging, linear LDS ----------------
#define GBM 128
#define GBN 64
#define GBK 64
#define LDA 64   // linear (m97 pattern): gload_lds requires contiguous dest
template<int ACT, int OUTBF>
__device__ __forceinline__ void gemm_body(short* As, short* Bs,
    const __hip_bfloat16* __restrict__ A, const __hip_bfloat16* __restrict__ BT,
    const float* __restrict__ bias, void* __restrict__ outv,
    const float* __restrict__ residual, int N, int K, int row0, int col0) {
    int tid = threadIdx.x;
    int lane = tid & 63, wid = tid >> 6;
    int wr = wid >> 1, wc = wid & 1;
    int lr = lane & 15, lk = lane >> 4;
    int lrow = lane >> 3, lcol = (lane & 7) * 8;   // gload_lds source mapping
    f32x4 acc[4][2] = {};
    for (int kt = 0; kt < K; kt += GBK) {
        // A: wave wid stages rows wid*32 .. +31 (4 instrs x 8 rows x 128B)
        #pragma unroll
        for (int i = 0; i < 4; ++i) {
            int r0 = wid * 32 + i * 8;
            const __hip_bfloat16* gsrc = A + (size_t)(row0 + r0 + lrow) * K + kt + lcol;
            __builtin_amdgcn_global_load_lds((gas_t*)gsrc, (las_t*)&As[r0 * LDA], 16, 0, 0);
        }
        // B: wave wid stages rows wid*16 .. +15 (2 instrs)
        #pragma unroll
        for (int i = 0; i < 2; ++i) {
            int r0 = wid * 16 + i * 8;
            const __hip_bfloat16* gsrc = BT + (size_t)(col0 + r0 + lrow) * K + kt + lcol;
            __builtin_amdgcn_global_load_lds((gas_t*)gsrc, (las_t*)&Bs[r0 * LDA], 16, 0, 0);
        }
        __syncthreads();
        #pragma unroll
        for (int ks = 0; ks < 2; ++ks) {
            bf16x8 bfr[2];
            #pragma unroll
            for (int n = 0; n < 2; ++n)
                bfr[n] = *(const bf16x8*)&Bs[(wc * 32 + n * 16 + lr) * LDA + ks * 32 + lk * 8];
            #pragma unroll
            for (int m = 0; m < 4; ++m) {
                bf16x8 afr = *(const bf16x8*)&As[(wr * 64 + m * 16 + lr) * LDA + ks * 32 + lk * 8];
                #pragma unroll
                for (int n = 0; n < 2; ++n)
                    acc[m][n] = __builtin_amdgcn_mfma_f32_16x16x32_bf16(afr, bfr[n], acc[m][n], 0, 0, 0);
            }
        }
        __syncthreads();
    }
    float bv[2];
    #pragma unroll
    for (int n = 0; n < 2; ++n) bv[n] = bias[col0 + wc * 32 + n * 16 + lr];
    #pragma unroll
    for (int m = 0; m < 4; ++m) {
        #pragma unroll
        for (int n = 0; n < 2; ++n) {
            int col = col0 + wc * 32 + n * 16 + lr;
            #pragma unroll
            for (int r = 0; r < 4; ++r) {
                int row = row0 + wr * 64 + m * 16 + lk * 4 + r;
                float v = acc[m][n][r] + bv[n];
                if (ACT == 1) v = 0.5f * v * (1.0f + erff(v * 0.70710678118654752f));
                size_t oi = (size_t)row * N + col;
                if (residual) v += residual[oi];
                if (OUTBF) ((__hip_bfloat16*)outv)[oi] = __float2bfloat16(v);
                else ((float*)outv)[oi] = v;
            }
        }
    }
}

template<int ACT, int OUTBF>
__global__ __launch_bounds__(256) void mfma_gemm_kernel(
    const __hip_bfloat16* __restrict__ A, const __hip_bfloat16* __restrict__ BT,
    const float* __restrict__ bias, void* __restrict__ outv,
    const float* __restrict__ residual, int M, int N, int K) {
    __shared__ short As[GBM * LDA];
    __shared__ short Bs[GBN * LDA];
    gemm_body<ACT, OUTBF>(As, Bs, A, BT, bias, outv, residual, N, K,
                          blockIdx.y * GBM, blockIdx.x * GBN);
}

// dual GEMM: xq (bx<4, M=8192,N=256) | xkv (bx>=4, M=512,N=512)
struct GemmPair {
    const __hip_bfloat16 *A1, *B1; const float* bias1; void* out1;
    const __hip_bfloat16 *A2, *B2; const float* bias2; void* out2;
};
__global__ __launch_bounds__(256) void dual_gemm_kernel(GemmPair p) {
    __shared__ short As[GBM * LDA];
    __shared__ short Bs[GBN * LDA];
    if (blockIdx.x < 4) {
        gemm_body<0, 1>(As, Bs, p.A1, p.B1, p.bias1, p.out1, nullptr, 256, 256,
                        blockIdx.y * GBM, blockIdx.x * GBN);
    } else {
        int row0 = blockIdx.y * GBM;
        if (row0 >= 512) return;
        gemm_body<0, 1>(As, Bs, p.A2, p.B2, p.bias2, p.out2, nullptr, 512, 256,
                        row0, (blockIdx.x - 4) * GBN);
    }
}

// ---------------- cluster attention v9: v8 + XCD partition swizzle ----------------
// qkv bf16 [8192][768]: q at col h*32+c; K+V region at 256 + h*64 (+32 for V).
// XCD = blockIdx%8 (heuristic): give XCDs 0-3 only batch 0 rows, 4-7 batch 1 ->
// per-XCD L2 working set halves (12.6 -> 6.3 MB).
#define KVSTR 520
__global__ __launch_bounds__(512) void cluster_attn_kernel(
    const __hip_bfloat16* __restrict__ qkvh,
    const int* __restrict__ member_idx, const int* __restrict__ cluster_mask,
    const int* __restrict__ pe_idx, const float* __restrict__ pet,
    const float* __restrict__ blank_k, const float* __restrict__ blank_v,
    __hip_bfloat16* __restrict__ outp) {
    const short* qkv = (const short*)qkvh;
    __shared__ short s_kv[48 * KVSTR];   // 49,920 B
    __shared__ float s_pm[48 * 9];       // pe+mask per [m][h], pad 9
    __shared__ float s_q[256];
    int tid = threadIdx.x;
    int bid = blockIdx.x;
    int row = ((bid & 7) << 10) | (bid >> 3);   // XCD partition: XCD x -> rows x*1024..+1023
    int b = row >> 12;

    // ---- stage K/V: wave w copies members {w, w+8, ...}; 64 lanes x 16B contiguous ----
    {
        int w = tid >> 6, l = tid & 63;
        #pragma unroll
        for (int r = 0; r < 6; ++r) {
            int m = w + r * 8;
            int im = member_idx[(size_t)row * MM + m];   // wave-uniform
            bf16x8 v8 = *(const bf16x8*)(qkv + ((size_t)(b * NN + im)) * 768 + 256 + l * 8);
            *(bf16x8*)&s_kv[m * KVSTR + l * 8] = v8;
        }
    }
    // ---- stage pe+mask (lanes 0-47) and q (threads 256-511) ----
    if (tid < MM) {
        float mb = cluster_mask[(size_t)row * MM + tid] ? 0.0f : -100.0f;
        int pidx = pe_idx[(size_t)row * MM + tid];
        const float4* pr = (const float4*)(pet + (size_t)pidx * 8);
        float4 p0 = pr[0], p1 = pr[1];
        float* dst = &s_pm[tid * 9];
        dst[0] = p0.x + mb; dst[1] = p0.y + mb; dst[2] = p0.z + mb; dst[3] = p0.w + mb;
        dst[4] = p1.x + mb; dst[5] = p1.y + mb; dst[6] = p1.z + mb; dst[7] = p1.w + mb;
    } else if (tid >= 256) {
        s_q[tid - 256] = bf2f(qkv[(size_t)row * 768 + (tid - 256)]);
    }
    __syncthreads();

    // ---- per-head attention (wave h) ----
    int h = tid >> 6, lane = tid & 63;
    const float* qf = s_q + h * CHDIM;   // broadcast reads
    float e = 0.0f;
    if (lane < MM) {
        const short* krow = s_kv + lane * KVSTR + h * 64;
        float d = s_pm[lane * 9 + h];
        #pragma unroll
        for (int c8 = 0; c8 < 4; ++c8) {
            bf16x8 kk = *(const bf16x8*)(krow + c8 * 8);
            d += qf[c8 * 8 + 0] * bf2f(kk[0]) + qf[c8 * 8 + 1] * bf2f(kk[1])
               + qf[c8 * 8 + 2] * bf2f(kk[2]) + qf[c8 * 8 + 3] * bf2f(kk[3])
               + qf[c8 * 8 + 4] * bf2f(kk[4]) + qf[c8 * 8 + 5] * bf2f(kk[5])
               + qf[c8 * 8 + 6] * bf2f(kk[6]) + qf[c8 * 8 + 7] * bf2f(kk[7]);
        }
        e = __expf(d);   // logits O(1); no-max softmax, exp(-100)->0
    } else if (lane == MM) {
        const float* bk = blank_k + h * CHDIM;
        float d = 0.0f;
        #pragma unroll
        for (int c = 0; c < CHDIM; ++c) d += qf[c] * bk[c];
        e = __expf(d);
    }
    float ssum = e;
    #pragma unroll
    for (int off = 32; off; off >>= 1) ssum += __shfl_xor(ssum, off, 64);
    float p = e / ssum;
    float p48 = __shfl(p, MM, 64);   // while all lanes active

    // ---- PV from LDS: lane = mg*8 + cq; member m = it*8+mg; 8B reads ----
    int mg = lane >> 3, cq = lane & 7;
    float a0 = 0.f, a1 = 0.f, a2 = 0.f, a3 = 0.f;
    #pragma unroll
    for (int it = 0; it < 6; ++it) {
        int m = it * 8 + mg;
        float pm = __shfl(p, m, 64);
        const short* vp = s_kv + m * KVSTR + h * 64 + 32 + cq * 4;
        ushort4 vv = *(const ushort4*)vp;
        a0 += pm * bf2f(vv.x); a1 += pm * bf2f(vv.y);
        a2 += pm * bf2f(vv.z); a3 += pm * bf2f(vv.w);
    }
    #pragma unroll
    for (int off = 8; off < 64; off <<= 1) {
        a0 += __shfl_xor(a0, off, 64);
        a1 += __shfl_xor(a1, off, 64);
        a2 += __shfl_xor(a2, off, 64);
        a3 += __shfl_xor(a3, off, 64);
    }
    if (lane < 8) {   // mg==0, cq=lane
        const float* bvp = blank_v + h * CHDIM + cq * 4;
        a0 += p48 * bvp[0]; a1 += p48 * bvp[1]; a2 += p48 * bvp[2]; a3 += p48 * bvp[3];
        ushort4 o4;
        o4.x = (unsigned short)f2bf(a0); o4.y = (unsigned short)f2bf(a1);
        o4.z = (unsigned short)f2bf(a2); o4.w = (unsigned short)f2bf(a3);
        *(ushort4*)((unsigned short*)outp + (size_t)row * CC + h * CHDIM + cq * 4) = o4;
    }
}

// ---------------- cross attention v4.1: MFMA flash-style, bf16 K/V input ----------------
#define KSLD 40
#define PVLD 264
__global__ __launch_bounds__(256) void cross_attn_kernel(
    const __hip_bfloat16* __restrict__ xq,   // [8192][256] bf16, scaled
    const __hip_bfloat16* __restrict__ xkvh, // [512][512] bf16: k at h*32+c, v at 256+h*32+c
    __hip_bfloat16* __restrict__ o) {
    const short* xkv = (const short*)xkvh;
    extern __shared__ short lds[];
    short* Ks = lds;                 // 256*40
    short* Vt = lds + 256 * KSLD;    // 32*264
    short* Ps = Vt + 32 * PVLD;      // 4*16*264
    int tid = threadIdx.x, lane = tid & 63, w = tid >> 6;
    int tile = blockIdx.x, h = blockIdx.y, b = blockIdx.z;
    int lr = lane & 15, g = lane >> 4;

    #pragma unroll
    for (int p = 0; p < 8; ++p) {
        int l = p * 32 + (tid >> 3);
        int c4 = (tid & 7) * 4;
        const short* kvrow = xkv + ((size_t)(b * LL + l)) * 512 + h * CHDIM;
        ushort4 kk = *(const ushort4*)(kvrow + c4);
        *(ushort4*)&Ks[l * KSLD + c4] = kk;
        ushort4 vv = *(const ushort4*)(kvrow + 256 + c4);
        Vt[(c4 + 0) * PVLD + l] = vv.x;
        Vt[(c4 + 1) * PVLD + l] = vv.y;
        Vt[(c4 + 2) * PVLD + l] = vv.z;
        Vt[(c4 + 3) * PVLD + l] = vv.w;
    }
    __syncthreads();

    int qrow = b * NN + tile * 64 + w * 16 + lr;
    bf16x8 afr = *(const bf16x8*)(xq + (size_t)qrow * CC + h * CHDIM + g * 8);
    f32x4 s[16];
    #pragma unroll
    for (int t = 0; t < 16; ++t) {
        bf16x8 kb = *(const bf16x8*)&Ks[(t * 16 + lr) * KSLD + g * 8];
        s[t] = __builtin_amdgcn_mfma_f32_16x16x32_bf16(afr, kb, (f32x4){0.f,0.f,0.f,0.f}, 0, 0, 0);
    }
    float rs[4] = {0.f, 0.f, 0.f, 0.f};
    #pragma unroll
    for (int t = 0; t < 16; ++t)
        #pragma unroll
        for (int r = 0; r < 4; ++r) { float e = __expf(s[t][r]); s[t][r] = e; rs[r] += e; }
    #pragma unroll
    for (int off = 1; off < 16; off <<= 1)
        #pragma unroll
        for (int r = 0; r < 4; ++r) rs[r] += __shfl_xor(rs[r], off, 64);
    short* Pw = Ps + w * 16 * PVLD;
    #pragma unroll
    for (int t = 0; t < 16; ++t)
        #pragma unroll
        for (int r = 0; r < 4; ++r)
            Pw[(g * 4 + r) * PVLD + t * 16 + lr] = f2bf(s[t][r]);
    f32x4 oacc[2] = {};
    #pragma unroll
    for (int kc = 0; kc < 8; ++kc) {
        bf16x8 pa = *(const bf16x8*)&Pw[lr * PVLD + kc * 32 + g * 8];
        #pragma unroll
        for (int n = 0; n < 2; ++n) {
            bf16x8 vb = *(const bf16x8*)&Vt[(n * 16 + lr) * PVLD + kc * 32 + g * 8];
            oacc[n] = __builtin_amdgcn_mfma_f32_16x16x32_bf16(pa, vb, oacc[n], 0, 0, 0);
        }
    }
    float inv[4];
    #pragma unroll
    for (int r = 0; r < 4; ++r) inv[r] = 1.0f / rs[r];
    #pragma unroll
    for (int n = 0; n < 2; ++n)
        #pragma unroll
        for (int r = 0; r < 4; ++r) {
            int orow = b * NN + tile * 64 + w * 16 + g * 4 + r;
            o[(size_t)orow * CC + h * CHDIM + n * 16 + lr] = __float2bfloat16(oacc[n][r] * inv[r]);
        }
}

extern "C" void kernel_launch(void* const* d_in, const int* in_sizes, int n_in,
                              void* d_out, int out_size, void* d_ws, size_t ws_size,
                              hipStream_t stream) {
    const float* feat        = (const float*)d_in[0];
    const float* memory      = (const float*)d_in[1];
    const int*   member_idx  = (const int*)d_in[2];
    const int*   cluster_mask= (const int*)d_in[3];
    const int*   pe_idx      = (const int*)d_in[4];
    const float* pre_table   = (const float*)d_in[6];
    const float* Wq    = (const float*)d_in[7];
    const float* bq    = (const float*)d_in[8];
    const float* Wkv   = (const float*)d_in[9];
    const float* bkv   = (const float*)d_in[10];
    const float* blank_k = (const float*)d_in[11];
    const float* blank_v = (const float*)d_in[12];
    const float* Wpe   = (const float*)d_in[13];
    const float* bpe   = (const float*)d_in[14];
    const float* Wproj = (const float*)d_in[15];
    const float* bproj = (const float*)d_in[16];
    const float* g1    = (const float*)d_in[17];
    const float* be1   = (const float*)d_in[18];
    const float* g2    = (const float*)d_in[19];
    const float* be2   = (const float*)d_in[20];
    const float* xWq   = (const float*)d_in[21];
    const float* xbq   = (const float*)d_in[22];
    const float* xWk   = (const float*)d_in[23];
    const float* xbk   = (const float*)d_in[24];
    const float* xWv   = (const float*)d_in[25];
    const float* xbv   = (const float*)d_in[26];
    const float* xWo   = (const float*)d_in[27];
    const float* xbo   = (const float*)d_in[28];
    const float* xg    = (const float*)d_in[29];
    const float* xbe   = (const float*)d_in[30];
    const float* W1    = (const float*)d_in[31];
    const float* bf1   = (const float*)d_in[32];
    const float* W2    = (const float*)d_in[33];
    const float* bf2   = (const float*)d_in[34];
    float* out = (float*)d_out;
    float* ws  = (float*)d_ws;

    // workspace layout (float units)
    __hip_bfloat16* qkvBf = (__hip_bfloat16*)ws;              // [8192][768] bf16
    __hip_bfloat16* xqBf  = (__hip_bfloat16*)ws;              // alias (qkv dead after cluster_attn)
    __hip_bfloat16* xkvBf = (__hip_bfloat16*)(ws + 3145728);  // [512][512] bf16
    __hip_bfloat16* hBf   = (__hip_bfloat16*)(ws + 3276800);  // [8192][512] bf16
    float* feat1F = ws + 5373952;                             // [8192][256] f32
    __hip_bfloat16* aBf   = (__hip_bfloat16*)(ws + 7471104);  // [8192][256] bf16
    __hip_bfloat16* oBf   = (__hip_bfloat16*)(ws + 8519680);  // [8192][256] bf16
    __hip_bfloat16* WqkvT = (__hip_bfloat16*)(ws + 9568256);  // [768][256]
    __hip_bfloat16* WprojT= (__hip_bfloat16*)(ws + 9666560);  // [256][256]
    __hip_bfloat16* xWqT  = (__hip_bfloat16*)(ws + 9699328);
    __hip_bfloat16* xWoT  = (__hip_bfloat16*)(ws + 9732096);
    __hip_bfloat16* xWkvT = (__hip_bfloat16*)(ws + 9764864);  // [512][256]
    __hip_bfloat16* W1T   = (__hip_bfloat16*)(ws + 9830400);  // [512][256]
    __hip_bfloat16* W2T   = (__hip_bfloat16*)(ws + 9895936);  // [256][512]
    __hip_bfloat16* memBf = (__hip_bfloat16*)(ws + 9961472);  // [512][256]
    float* pet   = ws + 10027008;                             // 80000
    float* bqkv  = ws + 10107008;                             // 768
    float* xbkv  = ws + 10107776;                             // 512
    float* xbqS  = ws + 10108288;                             // 256

    const float scale = 0.17677669529663689f; // 1/sqrt(32)

    // ---- prep (single launch) ----
    WtArgs wa;
    wa.d[0] = { Wq,    WqkvT,          256, 256, 0,   scale };
    wa.d[1] = { Wkv,   WqkvT + 65536,  256, 512, 64,  1.0f };
    wa.d[2] = { Wproj, WprojT,         256, 256, 192, 1.0f };
    wa.d[3] = { xWq,   xWqT,           256, 256, 256, scale };
    wa.d[4] = { xWk,   xWkvT,          256, 256, 320, 1.0f };
    wa.d[5] = { xWv,   xWkvT + 65536,  256, 256, 384, 1.0f };
    wa.d[6] = { xWo,   xWoT,           256, 256, 448, 1.0f };
    wa.d[7] = { W1,    W1T,            256, 512, 512, 1.0f };
    wa.d[8] = { W2,    W2T,            512, 256, 640, 1.0f };
    prep_all_kernel<<<768 + 831, 256, 0, stream>>>(wa, pre_table, Wpe, bpe, pet,
                                                   bq, bkv, xbk, xbv, xbq, scale,
                                                   bqkv, xbkv, xbqS, memory, memBf);

    // ---- block ----
    ln_kernel<<<ROWS / 4, 256, 0, stream>>>(feat, g1, be1, aBf);
    mfma_gemm_kernel<0,1><<<dim3(12, 64), 256, 0, stream>>>(aBf, WqkvT, bqkv, qkvBf, nullptr, ROWS, 768, 256);
    cluster_attn_kernel<<<ROWS, 512, 0, stream>>>(qkvBf, member_idx, cluster_mask, pe_idx, pet, blank_k, blank_v, oBf);
    mfma_gemm_kernel<0,0><<<dim3(4, 64), 256, 0, stream>>>(oBf, WprojT, bproj, feat1F, feat, ROWS, 256, 256);
    ln_kernel<<<ROWS / 4, 256, 0, stream>>>(feat1F, xg, xbe, aBf);
    {
        GemmPair gp;
        gp.A1 = aBf;   gp.B1 = xWqT;  gp.bias1 = xbqS; gp.out1 = xqBf;
        gp.A2 = memBf; gp.B2 = xWkvT; gp.bias2 = xbkv; gp.out2 = xkvBf;
        dual_gemm_kernel<<<dim3(12, 64), 256, 0, stream>>>(gp);
    }
    {
        size_t xlds = (256 * KSLD + 32 * PVLD + 4 * 16 * PVLD) * sizeof(short);
        cross_attn_kernel<<<dim3(NN / 64, HH, BB), 256, xlds, stream>>>(xqBf, xkvBf, oBf);
    }
    mfma_gemm_kernel<0,0><<<dim3(4, 64), 256, 0, stream>>>(oBf, xWoT, xbo, out, feat1F, ROWS, 256, 256);
    ln_kernel<<<ROWS / 4, 256, 0, stream>>>(out, g2, be2, aBf);
    mfma_gemm_kernel<1,1><<<dim3(8, 64), 256, 0, stream>>>(aBf, W1T, bf1, hBf, nullptr, ROWS, HIDD, 256);
    mfma_gemm_kernel<0,0><<<dim3(4, 64), 256, 0, stream>>>(hBf, W2T, bf2, out, out, ROWS, 256, HIDD);
}

// Round 13
// 148.613 us; speedup vs baseline: 1.1068x; 1.1068x over previous
//
#include <hip/hip_runtime.h>
#include <hip/hip_bf16.h>
#include <hip/hip_fp8.h>
#include <math.h>

// Problem constants
#define BB 2
#define NN 4096
#define CC 256
#define HH 8
#define MM 48
#define TT 10000
#define LL 256
#define CHDIM 32
#define HIDD 512
#define ROWS (BB*NN)   // 8192

typedef __attribute__((ext_vector_type(8))) short bf16x8;
typedef __attribute__((ext_vector_type(4))) float f32x4;
typedef __attribute__((ext_vector_type(2))) float f32x2;

static __device__ __forceinline__ short f2bf(float x) {
    __hip_bfloat16 h = __float2bfloat16(x);
    return *reinterpret_cast<short*>(&h);
}
static __device__ __forceinline__ float bf2f(short s) {
    unsigned int u = ((unsigned int)(unsigned short)s) << 16;
    union { unsigned int u; float f; } c; c.u = u;
    return c.f;
}

// ---------------- weight transpose descriptors ----------------
struct WtDesc { const float* src; __hip_bfloat16* dst; int K; int N; int tile0; float scl; };
struct WtArgs { WtDesc d[9]; };

// ---------------- merged prep: weight transpose | pe_table | bias | memory->bf16 ----------------
__global__ __launch_bounds__(256) void prep_all_kernel(WtArgs a,
    const float* __restrict__ pre, const float* __restrict__ Wpe,
    const float* __restrict__ bpe, float* __restrict__ pet,
    const float* __restrict__ bq, const float* __restrict__ bkv,
    const float* __restrict__ xbk, const float* __restrict__ xbv,
    const float* __restrict__ xbq, float scale,
    float* __restrict__ bqkv, float* __restrict__ xbkv, float* __restrict__ xbqS,
    const float* __restrict__ memory, __hip_bfloat16* __restrict__ memBf) {
    __shared__ float tile[32][33];
    int bid = blockIdx.x, tid = threadIdx.x;
    if (bid < 768) {
        int mi = 0;
        #pragma unroll
        for (int i = 1; i < 9; ++i) if (bid >= a.d[i].tile0) mi = i;
        WtDesc dsc = a.d[mi];
        int t = bid - dsc.tile0;
        int tiles_n = dsc.N >> 5;
        int k0 = (t / tiles_n) * 32, n0 = (t % tiles_n) * 32;
        int tx = tid & 31, ty = tid >> 5;   // 32x8
        #pragma unroll
        for (int i = 0; i < 32; i += 8)
            tile[ty + i][tx] = dsc.src[(size_t)(k0 + ty + i) * dsc.N + n0 + tx];
        __syncthreads();
        #pragma unroll
        for (int i = 0; i < 32; i += 8)
            dsc.dst[(size_t)(n0 + ty + i) * dsc.K + k0 + tx] = __float2bfloat16(tile[tx][ty + i] * dsc.scl);
        return;
    }
    bid -= 768;
    if (bid < 313) {
        int i = bid * 256 + tid;
        if (i >= TT * HH) return;
        int t = i / HH, h = i % HH;
        float s = bpe[h];
        #pragma unroll
        for (int j = 0; j < 5; ++j) s += pre[t * 5 + j] * Wpe[j * HH + h];
        pet[i] = s;
    } else if (bid < 319) {
        int i = (bid - 313) * 256 + tid;
        if (i < 256) bqkv[i] = bq[i] * scale;
        else if (i < 768) bqkv[i] = bkv[i - 256];
        else if (i < 1024) xbkv[i - 768] = xbk[i - 768];
        else if (i < 1280) xbkv[256 + i - 1024] = xbv[i - 1024];
        else if (i < 1536) xbqS[i - 1280] = xbq[i - 1280] * scale;
    } else {
        int i = (bid - 319) * 256 + tid;
        if (i < 131072) memBf[i] = __float2bfloat16(memory[i]);
    }
}

// ---------------- LayerNorm v2: wave-per-row, float4, no LDS/sync ----------------
__global__ __launch_bounds__(256) void ln_kernel(const float* __restrict__ in,
                                                 const float* __restrict__ g,
                                                 const float* __restrict__ b,
                                                 __hip_bfloat16* __restrict__ out) {
    int wave = threadIdx.x >> 6, lane = threadIdx.x & 63;
    int row = blockIdx.x * 4 + wave;
    float4 v = ((const float4*)(in + (size_t)row * CC))[lane];
    float s = (v.x + v.y) + (v.z + v.w);
    #pragma unroll
    for (int off = 32; off; off >>= 1) s += __shfl_xor(s, off, 64);
    float mu = s * (1.0f / 256.0f);
    float dx = v.x - mu, dy = v.y - mu, dz = v.z - mu, dw = v.w - mu;
    float s2 = (dx * dx + dy * dy) + (dz * dz + dw * dw);
    #pragma unroll
    for (int off = 32; off; off >>= 1) s2 += __shfl_xor(s2, off, 64);
    float rs = rsqrtf(s2 * (1.0f / 256.0f) + 1e-5f);
    float4 g4 = ((const float4*)g)[lane];
    float4 b4 = ((const float4*)b)[lane];
    ushort4 o4;
    o4.x = (unsigned short)f2bf(dx * rs * g4.x + b4.x);
    o4.y = (unsigned short)f2bf(dy * rs * g4.y + b4.y);
    o4.z = (unsigned short)f2bf(dz * rs * g4.z + b4.z);
    o4.w = (unsigned short)f2bf(dw * rs * g4.w + b4.w);
    *(ushort4*)((unsigned short*)out + (size_t)row * CC + lane * 4) = o4;
}

// ---------------- MFMA bf16 GEMM body (R11 reg-staged, padded LDS) ----------------
// OUTM: 0 = f32 out, 1 = bf16 out, 2 = qkv-split (col<256 -> bf16 q, col>=256 -> fp8 kv in outv2)
#define GBM 128
#define GBN 64
#define GBK 64
#define LDA 72   // 64 + 8 pad (bf16 units)
template<int ACT, int OUTM>
__device__ __forceinline__ void gemm_body(short* As, short* Bs,
    const __hip_bfloat16* __restrict__ A, const __hip_bfloat16* __restrict__ BT,
    const float* __restrict__ bias, void* __restrict__ outv,
    const float* __restrict__ residual, int N, int K, int row0, int col0,
    void* __restrict__ outv2) {
    int tid = threadIdx.x;
    int lane = tid & 63, wid = tid >> 6;
    int wr = wid >> 1, wc = wid & 1;
    int lr = lane & 15, lk = lane >> 4;
    f32x4 acc[4][2] = {};
    for (int kt = 0; kt < K; kt += GBK) {
        #pragma unroll
        for (int i = 0; i < 4; ++i) {
            int flat = tid + i * 256;
            int r = flat >> 3, kc = (flat & 7) * 8;
            *(bf16x8*)&As[r * LDA + kc] = *(const bf16x8*)(A + (size_t)(row0 + r) * K + kt + kc);
        }
        #pragma unroll
        for (int i = 0; i < 2; ++i) {
            int flat = tid + i * 256;
            int r = flat >> 3, kc = (flat & 7) * 8;
            *(bf16x8*)&Bs[r * LDA + kc] = *(const bf16x8*)(BT + (size_t)(col0 + r) * K + kt + kc);
        }
        __syncthreads();
        #pragma unroll
        for (int ks = 0; ks < 2; ++ks) {
            bf16x8 bfr[2];
            #pragma unroll
            for (int n = 0; n < 2; ++n)
                bfr[n] = *(const bf16x8*)&Bs[(wc * 32 + n * 16 + lr) * LDA + ks * 32 + lk * 8];
            #pragma unroll
            for (int m = 0; m < 4; ++m) {
                bf16x8 afr = *(const bf16x8*)&As[(wr * 64 + m * 16 + lr) * LDA + ks * 32 + lk * 8];
                #pragma unroll
                for (int n = 0; n < 2; ++n)
                    acc[m][n] = __builtin_amdgcn_mfma_f32_16x16x32_bf16(afr, bfr[n], acc[m][n], 0, 0, 0);
            }
        }
        __syncthreads();
    }
    float bv[2];
    #pragma unroll
    for (int n = 0; n < 2; ++n) bv[n] = bias[col0 + wc * 32 + n * 16 + lr];
    #pragma unroll
    for (int m = 0; m < 4; ++m) {
        #pragma unroll
        for (int n = 0; n < 2; ++n) {
            int col = col0 + wc * 32 + n * 16 + lr;
            #pragma unroll
            for (int r = 0; r < 4; ++r) {
                int row = row0 + wr * 64 + m * 16 + lk * 4 + r;
                float v = acc[m][n][r] + bv[n];
                if (ACT == 1) v = 0.5f * v * (1.0f + erff(v * 0.70710678118654752f));
                if (OUTM == 2) {
                    if (col < 256) {
                        ((__hip_bfloat16*)outv)[(size_t)row * 256 + col] = __float2bfloat16(v);
                    } else {
                        __hip_fp8_e4m3 f8(v);
                        ((unsigned char*)outv2)[(size_t)row * 512 + (col - 256)] = f8.__x;
                    }
                } else {
                    size_t oi = (size_t)row * N + col;
                    if (residual) v += residual[oi];
                    if (OUTM == 1) ((__hip_bfloat16*)outv)[oi] = __float2bfloat16(v);
                    else ((float*)outv)[oi] = v;
                }
            }
        }
    }
}

template<int ACT, int OUTM>
__global__ __launch_bounds__(256) void mfma_gemm_kernel(
    const __hip_bfloat16* __restrict__ A, const __hip_bfloat16* __restrict__ BT,
    const float* __restrict__ bias, void* __restrict__ outv,
    const float* __restrict__ residual, int M, int N, int K,
    void* __restrict__ outv2) {
    __shared__ short As[GBM * LDA];
    __shared__ short Bs[GBN * LDA];
    gemm_body<ACT, OUTM>(As, Bs, A, BT, bias, outv, residual, N, K,
                         blockIdx.y * GBM, blockIdx.x * GBN, outv2);
}

// dual GEMM: xq (bx<4, M=8192,N=256) | xkv (bx>=4, M=512,N=512)
struct GemmPair {
    const __hip_bfloat16 *A1, *B1; const float* bias1; void* out1;
    const __hip_bfloat16 *A2, *B2; const float* bias2; void* out2;
};
__global__ __launch_bounds__(256) void dual_gemm_kernel(GemmPair p) {
    __shared__ short As[GBM * LDA];
    __shared__ short Bs[GBN * LDA];
    if (blockIdx.x < 4) {
        gemm_body<0, 1>(As, Bs, p.A1, p.B1, p.bias1, p.out1, nullptr, 256, 256,
                        blockIdx.y * GBM, blockIdx.x * GBN, nullptr);
    } else {
        int row0 = blockIdx.y * GBM;
        if (row0 >= 512) return;
        gemm_body<0, 1>(As, Bs, p.A2, p.B2, p.bias2, p.out2, nullptr, 512, 256,
                        row0, (blockIdx.x - 4) * GBN, nullptr);
    }
}

// ---------------- cluster attention v10: fp8 KV (L2-resident per XCD) ----------------
// q bf16 [8192][256]; kv fp8 e4m3 [8192][512]: k at h*64+c, v at h*64+32+c.
// Per-batch KV = 2.1 MB < 4 MB per-XCD L2 (with XCD batch partition) -> gathers hit L2.
#define KVSTR8 528   // bytes per member in LDS (512 + 16 pad)
__global__ __launch_bounds__(512) void cluster_attn_kernel(
    const __hip_bfloat16* __restrict__ qh,
    const unsigned char* __restrict__ kv8,
    const int* __restrict__ member_idx, const int* __restrict__ cluster_mask,
    const int* __restrict__ pe_idx, const float* __restrict__ pet,
    const float* __restrict__ blank_k, const float* __restrict__ blank_v,
    __hip_bfloat16* __restrict__ outp) {
    const short* qg = (const short*)qh;
    __shared__ unsigned char s_kv[48 * KVSTR8];   // 25,344 B
    __shared__ float s_pm[48 * 9];                // pe+mask per [m][h]
    __shared__ float s_q[256];
    int tid = threadIdx.x;
    int bid = blockIdx.x;
    int row = ((bid & 7) << 10) | (bid >> 3);   // XCD partition: batch b on XCD b*4..b*4+3
    int b = row >> 12;

    // ---- stage K/V fp8: wave w copies members {w, w+8, ...}; 64 lanes x 8B contiguous ----
    {
        int w = tid >> 6, l = tid & 63;
        #pragma unroll
        for (int r = 0; r < 6; ++r) {
            int m = w + r * 8;
            int im = member_idx[(size_t)row * MM + m];   // wave-uniform
            uint2 v8 = *(const uint2*)(kv8 + ((size_t)(b * NN + im)) * 512 + l * 8);
            *(uint2*)&s_kv[m * KVSTR8 + l * 8] = v8;
        }
    }
    // ---- stage pe+mask (lanes 0-47) and q (threads 256-511) ----
    if (tid < MM) {
        float mb = cluster_mask[(size_t)row * MM + tid] ? 0.0f : -100.0f;
        int pidx = pe_idx[(size_t)row * MM + tid];
        const float4* pr = (const float4*)(pet + (size_t)pidx * 8);
        float4 p0 = pr[0], p1 = pr[1];
        float* dst = &s_pm[tid * 9];
        dst[0] = p0.x + mb; dst[1] = p0.y + mb; dst[2] = p0.z + mb; dst[3] = p0.w + mb;
        dst[4] = p1.x + mb; dst[5] = p1.y + mb; dst[6] = p1.z + mb; dst[7] = p1.w + mb;
    } else if (tid >= 256) {
        s_q[tid - 256] = bf2f(qg[(size_t)row * CC + (tid - 256)]);
    }
    __syncthreads();

    // ---- per-head attention (wave h) ----
    int h = tid >> 6, lane = tid & 63;
    const float* qf = s_q + h * CHDIM;   // broadcast reads
    float e = 0.0f;
    if (lane < MM) {
        const unsigned int* kp = (const unsigned int*)(s_kv + lane * KVSTR8 + h * 64);
        float d = s_pm[lane * 9 + h];
        #pragma unroll
        for (int u = 0; u < 8; ++u) {
            unsigned int kw = kp[u];
            f32x2 k01 = __builtin_amdgcn_cvt_pk_f32_fp8(kw, 0);
            f32x2 k23 = __builtin_amdgcn_cvt_pk_f32_fp8(kw, 1);
            d += qf[u * 4 + 0] * k01.x + qf[u * 4 + 1] * k01.y
               + qf[u * 4 + 2] * k23.x + qf[u * 4 + 3] * k23.y;
        }
        e = __expf(d);   // logits O(1); no-max softmax, exp(-100)->0
    } else if (lane == MM) {
        const float* bk = blank_k + h * CHDIM;
        float d = 0.0f;
        #pragma unroll
        for (int c = 0; c < CHDIM; ++c) d += qf[c] * bk[c];
        e = __expf(d);
    }
    float ssum = e;
    #pragma unroll
    for (int off = 32; off; off >>= 1) ssum += __shfl_xor(ssum, off, 64);
    float p = e / ssum;
    float p48 = __shfl(p, MM, 64);   // while all lanes active

    // ---- PV from LDS: lane = mg*8 + cq; member m = it*8+mg; 4B fp8 reads ----
    int mg = lane >> 3, cq = lane & 7;
    float a0 = 0.f, a1 = 0.f, a2 = 0.f, a3 = 0.f;
    #pragma unroll
    for (int it = 0; it < 6; ++it) {
        int m = it * 8 + mg;
        float pm = __shfl(p, m, 64);
        unsigned int vw = *(const unsigned int*)(s_kv + m * KVSTR8 + h * 64 + 32 + cq * 4);
        f32x2 v01 = __builtin_amdgcn_cvt_pk_f32_fp8(vw, 0);
        f32x2 v23 = __builtin_amdgcn_cvt_pk_f32_fp8(vw, 1);
        a0 += pm * v01.x; a1 += pm * v01.y;
        a2 += pm * v23.x; a3 += pm * v23.y;
    }
    #pragma unroll
    for (int off = 8; off < 64; off <<= 1) {
        a0 += __shfl_xor(a0, off, 64);
        a1 += __shfl_xor(a1, off, 64);
        a2 += __shfl_xor(a2, off, 64);
        a3 += __shfl_xor(a3, off, 64);
    }
    if (lane < 8) {   // mg==0, cq=lane
        const float* bvp = blank_v + h * CHDIM + cq * 4;
        a0 += p48 * bvp[0]; a1 += p48 * bvp[1]; a2 += p48 * bvp[2]; a3 += p48 * bvp[3];
        ushort4 o4;
        o4.x = (unsigned short)f2bf(a0); o4.y = (unsigned short)f2bf(a1);
        o4.z = (unsigned short)f2bf(a2); o4.w = (unsigned short)f2bf(a3);
        *(ushort4*)((unsigned short*)outp + (size_t)row * CC + h * CHDIM + cq * 4) = o4;
    }
}

// ---------------- cross attention v4.1: MFMA flash-style, bf16 K/V input ----------------
#define KSLD 40
#define PVLD 264
__global__ __launch_bounds__(256) void cross_attn_kernel(
    const __hip_bfloat16* __restrict__ xq,   // [8192][256] bf16, scaled
    const __hip_bfloat16* __restrict__ xkvh, // [512][512] bf16: k at h*32+c, v at 256+h*32+c
    __hip_bfloat16* __restrict__ o) {
    const short* xkv = (const short*)xkvh;
    extern __shared__ short lds[];
    short* Ks = lds;                 // 256*40
    short* Vt = lds + 256 * KSLD;    // 32*264
    short* Ps = Vt + 32 * PVLD;      // 4*16*264
    int tid = threadIdx.x, lane = tid & 63, w = tid >> 6;
    int tile = blockIdx.x, h = blockIdx.y, b = blockIdx.z;
    int lr = lane & 15, g = lane >> 4;

    #pragma unroll
    for (int p = 0; p < 8; ++p) {
        int l = p * 32 + (tid >> 3);
        int c4 = (tid & 7) * 4;
        const short* kvrow = xkv + ((size_t)(b * LL + l)) * 512 + h * CHDIM;
        ushort4 kk = *(const ushort4*)(kvrow + c4);
        *(ushort4*)&Ks[l * KSLD + c4] = kk;
        ushort4 vv = *(const ushort4*)(kvrow + 256 + c4);
        Vt[(c4 + 0) * PVLD + l] = vv.x;
        Vt[(c4 + 1) * PVLD + l] = vv.y;
        Vt[(c4 + 2) * PVLD + l] = vv.z;
        Vt[(c4 + 3) * PVLD + l] = vv.w;
    }
    __syncthreads();

    int qrow = b * NN + tile * 64 + w * 16 + lr;
    bf16x8 afr = *(const bf16x8*)(xq + (size_t)qrow * CC + h * CHDIM + g * 8);
    f32x4 s[16];
    #pragma unroll
    for (int t = 0; t < 16; ++t) {
        bf16x8 kb = *(const bf16x8*)&Ks[(t * 16 + lr) * KSLD + g * 8];
        s[t] = __builtin_amdgcn_mfma_f32_16x16x32_bf16(afr, kb, (f32x4){0.f,0.f,0.f,0.f}, 0, 0, 0);
    }
    float rs[4] = {0.f, 0.f, 0.f, 0.f};
    #pragma unroll
    for (int t = 0; t < 16; ++t)
        #pragma unroll
        for (int r = 0; r < 4; ++r) { float e = __expf(s[t][r]); s[t][r] = e; rs[r] += e; }
    #pragma unroll
    for (int off = 1; off < 16; off <<= 1)
        #pragma unroll
        for (int r = 0; r < 4; ++r) rs[r] += __shfl_xor(rs[r], off, 64);
    short* Pw = Ps + w * 16 * PVLD;
    #pragma unroll
    for (int t = 0; t < 16; ++t)
        #pragma unroll
        for (int r = 0; r < 4; ++r)
            Pw[(g * 4 + r) * PVLD + t * 16 + lr] = f2bf(s[t][r]);
    f32x4 oacc[2] = {};
    #pragma unroll
    for (int kc = 0; kc < 8; ++kc) {
        bf16x8 pa = *(const bf16x8*)&Pw[lr * PVLD + kc * 32 + g * 8];
        #pragma unroll
        for (int n = 0; n < 2; ++n) {
            bf16x8 vb = *(const bf16x8*)&Vt[(n * 16 + lr) * PVLD + kc * 32 + g * 8];
            oacc[n] = __builtin_amdgcn_mfma_f32_16x16x32_bf16(pa, vb, oacc[n], 0, 0, 0);
        }
    }
    float inv[4];
    #pragma unroll
    for (int r = 0; r < 4; ++r) inv[r] = 1.0f / rs[r];
    #pragma unroll
    for (int n = 0; n < 2; ++n)
        #pragma unroll
        for (int r = 0; r < 4; ++r) {
            int orow = b * NN + tile * 64 + w * 16 + g * 4 + r;
            o[(size_t)orow * CC + h * CHDIM + n * 16 + lr] = __float2bfloat16(oacc[n][r] * inv[r]);
        }
}

extern "C" void kernel_launch(void* const* d_in, const int* in_sizes, int n_in,
                              void* d_out, int out_size, void* d_ws, size_t ws_size,
                              hipStream_t stream) {
    const float* feat        = (const float*)d_in[0];
    const float* memory      = (const float*)d_in[1];
    const int*   member_idx  = (const int*)d_in[2];
    const int*   cluster_mask= (const int*)d_in[3];
    const int*   pe_idx      = (const int*)d_in[4];
    const float* pre_table   = (const float*)d_in[6];
    const float* Wq    = (const float*)d_in[7];
    const float* bq    = (const float*)d_in[8];
    const float* Wkv   = (const float*)d_in[9];
    const float* bkv   = (const float*)d_in[10];
    const float* blank_k = (const float*)d_in[11];
    const float* blank_v = (const float*)d_in[12];
    const float* Wpe   = (const float*)d_in[13];
    const float* bpe   = (const float*)d_in[14];
    const float* Wproj = (const float*)d_in[15];
    const float* bproj = (const float*)d_in[16];
    const float* g1    = (const float*)d_in[17];
    const float* be1   = (const float*)d_in[18];
    const float* g2    = (const float*)d_in[19];
    const float* be2   = (const float*)d_in[20];
    const float* xWq   = (const float*)d_in[21];
    const float* xbq   = (const float*)d_in[22];
    const float* xWk   = (const float*)d_in[23];
    const float* xbk   = (const float*)d_in[24];
    const float* xWv   = (const float*)d_in[25];
    const float* xbv   = (const float*)d_in[26];
    const float* xWo   = (const float*)d_in[27];
    const float* xbo   = (const float*)d_in[28];
    const float* xg    = (const float*)d_in[29];
    const float* xbe   = (const float*)d_in[30];
    const float* W1    = (const float*)d_in[31];
    const float* bf1   = (const float*)d_in[32];
    const float* W2    = (const float*)d_in[33];
    const float* bf2   = (const float*)d_in[34];
    float* out = (float*)d_out;
    float* ws  = (float*)d_ws;

    // workspace layout (float units)
    __hip_bfloat16* qBf   = (__hip_bfloat16*)ws;              // [8192][256] bf16 (1,048,576 fl)
    __hip_bfloat16* xqBf  = (__hip_bfloat16*)ws;              // alias (q dead after cluster_attn)
    unsigned char*  kv8   = (unsigned char*)(ws + 1048576);   // [8192][512] fp8 (1,048,576 fl)
    __hip_bfloat16* xkvBf = (__hip_bfloat16*)(ws + 2097152);  // [512][512] bf16 (131,072 fl)
    __hip_bfloat16* hBf   = (__hip_bfloat16*)(ws + 2228224);  // [8192][512] bf16 (2,097,152 fl)
    float* feat1F = ws + 4325376;                             // [8192][256] f32 (2,097,152 fl)
    __hip_bfloat16* aBf   = (__hip_bfloat16*)(ws + 6422528);  // [8192][256] bf16
    __hip_bfloat16* oBf   = (__hip_bfloat16*)(ws + 7471104);  // [8192][256] bf16
    __hip_bfloat16* WqkvT = (__hip_bfloat16*)(ws + 8519680);  // [768][256]
    __hip_bfloat16* WprojT= (__hip_bfloat16*)(ws + 8617984);  // [256][256]
    __hip_bfloat16* xWqT  = (__hip_bfloat16*)(ws + 8650752);
    __hip_bfloat16* xWoT  = (__hip_bfloat16*)(ws + 8683520);
    __hip_bfloat16* xWkvT = (__hip_bfloat16*)(ws + 8716288);  // [512][256]
    __hip_bfloat16* W1T   = (__hip_bfloat16*)(ws + 8781824);  // [512][256]
    __hip_bfloat16* W2T   = (__hip_bfloat16*)(ws + 8847360);  // [256][512]
    __hip_bfloat16* memBf = (__hip_bfloat16*)(ws + 8912896);  // [512][256]
    float* pet   = ws + 8978432;                              // 80000
    float* bqkv  = ws + 9058432;                              // 768
    float* xbkv  = ws + 9059200;                              // 512
    float* xbqS  = ws + 9059712;                              // 256

    const float scale = 0.17677669529663689f; // 1/sqrt(32)

    // ---- prep (single launch) ----
    WtArgs wa;
    wa.d[0] = { Wq,    WqkvT,          256, 256, 0,   scale };
    wa.d[1] = { Wkv,   WqkvT + 65536,  256, 512, 64,  1.0f };
    wa.d[2] = { Wproj, WprojT,         256, 256, 192, 1.0f };
    wa.d[3] = { xWq,   xWqT,           256, 256, 256, scale };
    wa.d[4] = { xWk,   xWkvT,          256, 256, 320, 1.0f };
    wa.d[5] = { xWv,   xWkvT + 65536,  256, 256, 384, 1.0f };
    wa.d[6] = { xWo,   xWoT,           256, 256, 448, 1.0f };
    wa.d[7] = { W1,    W1T,            256, 512, 512, 1.0f };
    wa.d[8] = { W2,    W2T,            512, 256, 640, 1.0f };
    prep_all_kernel<<<768 + 831, 256, 0, stream>>>(wa, pre_table, Wpe, bpe, pet,
                                                   bq, bkv, xbk, xbv, xbq, scale,
                                                   bqkv, xbkv, xbqS, memory, memBf);

    // ---- block ----
    ln_kernel<<<ROWS / 4, 256, 0, stream>>>(feat, g1, be1, aBf);
    mfma_gemm_kernel<0,2><<<dim3(12, 64), 256, 0, stream>>>(aBf, WqkvT, bqkv, qBf, nullptr, ROWS, 768, 256, kv8);
    cluster_attn_kernel<<<ROWS, 512, 0, stream>>>(qBf, kv8, member_idx, cluster_mask, pe_idx, pet, blank_k, blank_v, oBf);
    mfma_gemm_kernel<0,0><<<dim3(4, 64), 256, 0, stream>>>(oBf, WprojT, bproj, feat1F, feat, ROWS, 256, 256, nullptr);
    ln_kernel<<<ROWS / 4, 256, 0, stream>>>(feat1F, xg, xbe, aBf);
    {
        GemmPair gp;
        gp.A1 = aBf;   gp.B1 = xWqT;  gp.bias1 = xbqS; gp.out1 = xqBf;
        gp.A2 = memBf; gp.B2 = xWkvT; gp.bias2 = xbkv; gp.out2 = xkvBf;
        dual_gemm_kernel<<<dim3(12, 64), 256, 0, stream>>>(gp);
    }
    {
        size_t xlds = (256 * KSLD + 32 * PVLD + 4 * 16 * PVLD) * sizeof(short);
        cross_attn_kernel<<<dim3(NN / 64, HH, BB), 256, xlds, stream>>>(xqBf, xkvBf, oBf);
    }
    mfma_gemm_kernel<0,0><<<dim3(4, 64), 256, 0, stream>>>(oBf, xWoT, xbo, out, feat1F, ROWS, 256, 256, nullptr);
    ln_kernel<<<ROWS / 4, 256, 0, stream>>>(out, g2, be2, aBf);
    mfma_gemm_kernel<1,1><<<dim3(8, 64), 256, 0, stream>>>(aBf, W1T, bf1, hBf, nullptr, ROWS, HIDD, 256, nullptr);
    mfma_gemm_kernel<0,0><<<dim3(4, 64), 256, 0, stream>>>(hBf, W2T, bf2, out, out, ROWS, 256, HIDD, nullptr);
}

// Round 14
// 148.493 us; speedup vs baseline: 1.1077x; 1.0008x over previous
//
#include <hip/hip_runtime.h>
#include <hip/hip_bf16.h>
#include <hip/hip_fp8.h>
#include <math.h>

// Problem constants
#define BB 2
#define NN 4096
#define CC 256
#define HH 8
#define MM 48
#define TT 10000
#define LL 256
#define CHDIM 32
#define HIDD 512
#define ROWS (BB*NN)   // 8192

typedef __attribute__((ext_vector_type(8))) short bf16x8;
typedef __attribute__((ext_vector_type(4))) float f32x4;
typedef __attribute__((ext_vector_type(2))) float f32x2;

static __device__ __forceinline__ short f2bf(float x) {
    __hip_bfloat16 h = __float2bfloat16(x);
    return *reinterpret_cast<short*>(&h);
}
static __device__ __forceinline__ float bf2f(short s) {
    unsigned int u = ((unsigned int)(unsigned short)s) << 16;
    union { unsigned int u; float f; } c; c.u = u;
    return c.f;
}

// ---------------- weight transpose descriptors ----------------
struct WtDesc { const float* src; __hip_bfloat16* dst; int K; int N; int tile0; float scl; };
struct WtArgs { WtDesc d[9]; };

// ---------------- merged prep: weight transpose | pe_table | bias | memory->bf16 ----------------
__global__ __launch_bounds__(256) void prep_all_kernel(WtArgs a,
    const float* __restrict__ pre, const float* __restrict__ Wpe,
    const float* __restrict__ bpe, float* __restrict__ pet,
    const float* __restrict__ bq, const float* __restrict__ bkv,
    const float* __restrict__ xbk, const float* __restrict__ xbv,
    const float* __restrict__ xbq, float scale,
    float* __restrict__ bqkv, float* __restrict__ xbkv, float* __restrict__ xbqS,
    const float* __restrict__ memory, __hip_bfloat16* __restrict__ memBf) {
    __shared__ float tile[32][33];
    int bid = blockIdx.x, tid = threadIdx.x;
    if (bid < 768) {
        int mi = 0;
        #pragma unroll
        for (int i = 1; i < 9; ++i) if (bid >= a.d[i].tile0) mi = i;
        WtDesc dsc = a.d[mi];
        int t = bid - dsc.tile0;
        int tiles_n = dsc.N >> 5;
        int k0 = (t / tiles_n) * 32, n0 = (t % tiles_n) * 32;
        int tx = tid & 31, ty = tid >> 5;   // 32x8
        #pragma unroll
        for (int i = 0; i < 32; i += 8)
            tile[ty + i][tx] = dsc.src[(size_t)(k0 + ty + i) * dsc.N + n0 + tx];
        __syncthreads();
        #pragma unroll
        for (int i = 0; i < 32; i += 8)
            dsc.dst[(size_t)(n0 + ty + i) * dsc.K + k0 + tx] = __float2bfloat16(tile[tx][ty + i] * dsc.scl);
        return;
    }
    bid -= 768;
    if (bid < 313) {
        int i = bid * 256 + tid;
        if (i >= TT * HH) return;
        int t = i / HH, h = i % HH;
        float s = bpe[h];
        #pragma unroll
        for (int j = 0; j < 5; ++j) s += pre[t * 5 + j] * Wpe[j * HH + h];
        pet[i] = s;
    } else if (bid < 319) {
        int i = (bid - 313) * 256 + tid;
        if (i < 256) bqkv[i] = bq[i] * scale;
        else if (i < 768) bqkv[i] = bkv[i - 256];
        else if (i < 1024) xbkv[i - 768] = xbk[i - 768];
        else if (i < 1280) xbkv[256 + i - 1024] = xbv[i - 1024];
        else if (i < 1536) xbqS[i - 1280] = xbq[i - 1280] * scale;
    } else {
        int i = (bid - 319) * 256 + tid;
        if (i < 131072) memBf[i] = __float2bfloat16(memory[i]);
    }
}

// ---------------- LayerNorm v2: wave-per-row, float4, no LDS/sync ----------------
__global__ __launch_bounds__(256) void ln_kernel(const float* __restrict__ in,
                                                 const float* __restrict__ g,
                                                 const float* __restrict__ b,
                                                 __hip_bfloat16* __restrict__ out) {
    int wave = threadIdx.x >> 6, lane = threadIdx.x & 63;
    int row = blockIdx.x * 4 + wave;
    float4 v = ((const float4*)(in + (size_t)row * CC))[lane];
    float s = (v.x + v.y) + (v.z + v.w);
    #pragma unroll
    for (int off = 32; off; off >>= 1) s += __shfl_xor(s, off, 64);
    float mu = s * (1.0f / 256.0f);
    float dx = v.x - mu, dy = v.y - mu, dz = v.z - mu, dw = v.w - mu;
    float s2 = (dx * dx + dy * dy) + (dz * dz + dw * dw);
    #pragma unroll
    for (int off = 32; off; off >>= 1) s2 += __shfl_xor(s2, off, 64);
    float rs = rsqrtf(s2 * (1.0f / 256.0f) + 1e-5f);
    float4 g4 = ((const float4*)g)[lane];
    float4 b4 = ((const float4*)b)[lane];
    ushort4 o4;
    o4.x = (unsigned short)f2bf(dx * rs * g4.x + b4.x);
    o4.y = (unsigned short)f2bf(dy * rs * g4.y + b4.y);
    o4.z = (unsigned short)f2bf(dz * rs * g4.z + b4.z);
    o4.w = (unsigned short)f2bf(dw * rs * g4.w + b4.w);
    *(ushort4*)((unsigned short*)out + (size_t)row * CC + lane * 4) = o4;
}

// ---------------- MFMA bf16 GEMM body (reg-staged, padded LDS) ----------------
// OUTM: 0 = f32 out, 1 = bf16 out, 2 = qkv-split (col<256 -> bf16 q, col>=256 -> fp8 kv in outv2)
#define GBM 128
#define GBN 64
#define GBK 64
#define LDA 72   // 64 + 8 pad (bf16 units)
template<int ACT, int OUTM>
__device__ __forceinline__ void gemm_body(short* As, short* Bs,
    const __hip_bfloat16* __restrict__ A, const __hip_bfloat16* __restrict__ BT,
    const float* __restrict__ bias, void* __restrict__ outv,
    const float* __restrict__ residual, int N, int K, int row0, int col0,
    void* __restrict__ outv2) {
    int tid = threadIdx.x;
    int lane = tid & 63, wid = tid >> 6;
    int wr = wid >> 1, wc = wid & 1;
    int lr = lane & 15, lk = lane >> 4;
    f32x4 acc[4][2] = {};
    for (int kt = 0; kt < K; kt += GBK) {
        #pragma unroll
        for (int i = 0; i < 4; ++i) {
            int flat = tid + i * 256;
            int r = flat >> 3, kc = (flat & 7) * 8;
            *(bf16x8*)&As[r * LDA + kc] = *(const bf16x8*)(A + (size_t)(row0 + r) * K + kt + kc);
        }
        #pragma unroll
        for (int i = 0; i < 2; ++i) {
            int flat = tid + i * 256;
            int r = flat >> 3, kc = (flat & 7) * 8;
            *(bf16x8*)&Bs[r * LDA + kc] = *(const bf16x8*)(BT + (size_t)(col0 + r) * K + kt + kc);
        }
        __syncthreads();
        #pragma unroll
        for (int ks = 0; ks < 2; ++ks) {
            bf16x8 bfr[2];
            #pragma unroll
            for (int n = 0; n < 2; ++n)
                bfr[n] = *(const bf16x8*)&Bs[(wc * 32 + n * 16 + lr) * LDA + ks * 32 + lk * 8];
            #pragma unroll
            for (int m = 0; m < 4; ++m) {
                bf16x8 afr = *(const bf16x8*)&As[(wr * 64 + m * 16 + lr) * LDA + ks * 32 + lk * 8];
                #pragma unroll
                for (int n = 0; n < 2; ++n)
                    acc[m][n] = __builtin_amdgcn_mfma_f32_16x16x32_bf16(afr, bfr[n], acc[m][n], 0, 0, 0);
            }
        }
        __syncthreads();
    }
    float bv[2];
    #pragma unroll
    for (int n = 0; n < 2; ++n) bv[n] = bias[col0 + wc * 32 + n * 16 + lr];
    #pragma unroll
    for (int m = 0; m < 4; ++m) {
        #pragma unroll
        for (int n = 0; n < 2; ++n) {
            int col = col0 + wc * 32 + n * 16 + lr;
            #pragma unroll
            for (int r = 0; r < 4; ++r) {
                int row = row0 + wr * 64 + m * 16 + lk * 4 + r;
                float v = acc[m][n][r] + bv[n];
                if (ACT == 1) {
                    // tanh-GELU (sigmoid form): max |delta| vs erf-GELU ~3e-4
                    float z = v + 0.044715f * v * v * v;
                    v = v / (1.0f + __expf(-1.5957691216057308f * z));
                }
                if (OUTM == 2) {
                    if (col < 256) {
                        ((__hip_bfloat16*)outv)[(size_t)row * 256 + col] = __float2bfloat16(v);
                    } else {
                        __hip_fp8_e4m3 f8(v);
                        ((unsigned char*)outv2)[(size_t)row * 512 + (col - 256)] = f8.__x;
                    }
                } else {
                    size_t oi = (size_t)row * N + col;
                    if (residual) v += residual[oi];
                    if (OUTM == 1) ((__hip_bfloat16*)outv)[oi] = __float2bfloat16(v);
                    else ((float*)outv)[oi] = v;
                }
            }
        }
    }
}

template<int ACT, int OUTM>
__global__ __launch_bounds__(256) void mfma_gemm_kernel(
    const __hip_bfloat16* __restrict__ A, const __hip_bfloat16* __restrict__ BT,
    const float* __restrict__ bias, void* __restrict__ outv,
    const float* __restrict__ residual, int M, int N, int K,
    void* __restrict__ outv2) {
    __shared__ short As[GBM * LDA];
    __shared__ short Bs[GBN * LDA];
    gemm_body<ACT, OUTM>(As, Bs, A, BT, bias, outv, residual, N, K,
                         blockIdx.y * GBM, blockIdx.x * GBN, outv2);
}

// dual GEMM: xq (bx<4, M=8192,N=256) | xkv (bx>=4, M=512,N=512)
struct GemmPair {
    const __hip_bfloat16 *A1, *B1; const float* bias1; void* out1;
    const __hip_bfloat16 *A2, *B2; const float* bias2; void* out2;
};
__global__ __launch_bounds__(256) void dual_gemm_kernel(GemmPair p) {
    __shared__ short As[GBM * LDA];
    __shared__ short Bs[GBN * LDA];
    if (blockIdx.x < 4) {
        gemm_body<0, 1>(As, Bs, p.A1, p.B1, p.bias1, p.out1, nullptr, 256, 256,
                        blockIdx.y * GBM, blockIdx.x * GBN, nullptr);
    } else {
        int row0 = blockIdx.y * GBM;
        if (row0 >= 512) return;
        gemm_body<0, 1>(As, Bs, p.A2, p.B2, p.bias2, p.out2, nullptr, 512, 256,
                        row0, (blockIdx.x - 4) * GBN, nullptr);
    }
}

// ---------------- cluster attention v11: fp8 KV, b128 K reads, split-acc ILP ----------------
// q bf16 [8192][256]; kv fp8 e4m3 [8192][512]: k at h*64+c, v at h*64+32+c.
#define KVSTR8 528   // bytes per member in LDS (512 + 16 pad); 528 = 33*16 -> 16B aligned rows
__global__ __launch_bounds__(512) void cluster_attn_kernel(
    const __hip_bfloat16* __restrict__ qh,
    const unsigned char* __restrict__ kv8,
    const int* __restrict__ member_idx, const int* __restrict__ cluster_mask,
    const int* __restrict__ pe_idx, const float* __restrict__ pet,
    const float* __restrict__ blank_k, const float* __restrict__ blank_v,
    __hip_bfloat16* __restrict__ outp) {
    const short* qg = (const short*)qh;
    __shared__ unsigned char s_kv[48 * KVSTR8];   // 25,344 B
    __shared__ float s_pm[48 * 9];                // pe+mask per [m][h]
    __shared__ float s_q[256];
    int tid = threadIdx.x;
    int bid = blockIdx.x;
    int row = ((bid & 7) << 10) | (bid >> 3);   // XCD partition: batch b on XCD b*4..b*4+3
    int b = row >> 12;

    // ---- stage K/V fp8: wave w copies members {w, w+8, ...}; 64 lanes x 8B contiguous ----
    {
        int w = tid >> 6, l = tid & 63;
        #pragma unroll
        for (int r = 0; r < 6; ++r) {
            int m = w + r * 8;
            int im = member_idx[(size_t)row * MM + m];   // wave-uniform
            uint2 v8 = *(const uint2*)(kv8 + ((size_t)(b * NN + im)) * 512 + l * 8);
            *(uint2*)&s_kv[m * KVSTR8 + l * 8] = v8;
        }
    }
    // ---- stage pe+mask (lanes 0-47) and q (threads 256-511) ----
    if (tid < MM) {
        float mb = cluster_mask[(size_t)row * MM + tid] ? 0.0f : -100.0f;
        int pidx = pe_idx[(size_t)row * MM + tid];
        const float4* pr = (const float4*)(pet + (size_t)pidx * 8);
        float4 p0 = pr[0], p1 = pr[1];
        float* dst = &s_pm[tid * 9];
        dst[0] = p0.x + mb; dst[1] = p0.y + mb; dst[2] = p0.z + mb; dst[3] = p0.w + mb;
        dst[4] = p1.x + mb; dst[5] = p1.y + mb; dst[6] = p1.z + mb; dst[7] = p1.w + mb;
    } else if (tid >= 256) {
        s_q[tid - 256] = bf2f(qg[(size_t)row * CC + (tid - 256)]);
    }
    __syncthreads();

    // ---- per-head attention (wave h) ----
    int h = tid >> 6, lane = tid & 63;
    const float* qf = s_q + h * CHDIM;   // broadcast reads
    float e = 0.0f;
    if (lane < MM) {
        const uint4* kp = (const uint4*)(s_kv + lane * KVSTR8 + h * 64);
        uint4 kw0 = kp[0];
        uint4 kw1 = kp[1];
        unsigned int kws[8] = {kw0.x, kw0.y, kw0.z, kw0.w, kw1.x, kw1.y, kw1.z, kw1.w};
        float d0 = s_pm[lane * 9 + h], d1 = 0.0f;
        #pragma unroll
        for (int u = 0; u < 8; u += 2) {
            f32x2 a01 = __builtin_amdgcn_cvt_pk_f32_fp8(kws[u], 0);
            f32x2 a23 = __builtin_amdgcn_cvt_pk_f32_fp8(kws[u], 1);
            f32x2 b01 = __builtin_amdgcn_cvt_pk_f32_fp8(kws[u + 1], 0);
            f32x2 b23 = __builtin_amdgcn_cvt_pk_f32_fp8(kws[u + 1], 1);
            d0 += qf[u * 4 + 0] * a01.x + qf[u * 4 + 1] * a01.y
                + qf[u * 4 + 2] * a23.x + qf[u * 4 + 3] * a23.y;
            d1 += qf[u * 4 + 4] * b01.x + qf[u * 4 + 5] * b01.y
                + qf[u * 4 + 6] * b23.x + qf[u * 4 + 7] * b23.y;
        }
        e = __expf(d0 + d1);   // logits O(1); no-max softmax, exp(-100)->0
    } else if (lane == MM) {
        const float* bk = blank_k + h * CHDIM;
        float d = 0.0f;
        #pragma unroll
        for (int c = 0; c < CHDIM; ++c) d += qf[c] * bk[c];
        e = __expf(d);
    }
    float ssum = e;
    #pragma unroll
    for (int off = 32; off; off >>= 1) ssum += __shfl_xor(ssum, off, 64);
    float p = e / ssum;
    float p48 = __shfl(p, MM, 64);   // while all lanes active

    // ---- PV from LDS: lane = mg*8 + cq; member m = it*8+mg; prefetched 4B fp8 reads ----
    int mg = lane >> 3, cq = lane & 7;
    unsigned int vw[6];
    #pragma unroll
    for (int it = 0; it < 6; ++it)
        vw[it] = *(const unsigned int*)(s_kv + (it * 8 + mg) * KVSTR8 + h * 64 + 32 + cq * 4);
    float a0 = 0.f, a1 = 0.f, a2 = 0.f, a3 = 0.f;
    #pragma unroll
    for (int it = 0; it < 6; ++it) {
        int m = it * 8 + mg;
        float pm = __shfl(p, m, 64);
        f32x2 v01 = __builtin_amdgcn_cvt_pk_f32_fp8(vw[it], 0);
        f32x2 v23 = __builtin_amdgcn_cvt_pk_f32_fp8(vw[it], 1);
        a0 += pm * v01.x; a1 += pm * v01.y;
        a2 += pm * v23.x; a3 += pm * v23.y;
    }
    #pragma unroll
    for (int off = 8; off < 64; off <<= 1) {
        a0 += __shfl_xor(a0, off, 64);
        a1 += __shfl_xor(a1, off, 64);
        a2 += __shfl_xor(a2, off, 64);
        a3 += __shfl_xor(a3, off, 64);
    }
    if (lane < 8) {   // mg==0, cq=lane
        const float* bvp = blank_v + h * CHDIM + cq * 4;
        a0 += p48 * bvp[0]; a1 += p48 * bvp[1]; a2 += p48 * bvp[2]; a3 += p48 * bvp[3];
        ushort4 o4;
        o4.x = (unsigned short)f2bf(a0); o4.y = (unsigned short)f2bf(a1);
        o4.z = (unsigned short)f2bf(a2); o4.w = (unsigned short)f2bf(a3);
        *(ushort4*)((unsigned short*)outp + (size_t)row * CC + h * CHDIM + cq * 4) = o4;
    }
}

// ---------------- cross attention v4.1: MFMA flash-style, bf16 K/V input ----------------
#define KSLD 40
#define PVLD 264
__global__ __launch_bounds__(256) void cross_attn_kernel(
    const __hip_bfloat16* __restrict__ xq,   // [8192][256] bf16, scaled
    const __hip_bfloat16* __restrict__ xkvh, // [512][512] bf16: k at h*32+c, v at 256+h*32+c
    __hip_bfloat16* __restrict__ o) {
    const short* xkv = (const short*)xkvh;
    extern __shared__ short lds[];
    short* Ks = lds;                 // 256*40
    short* Vt = lds + 256 * KSLD;    // 32*264
    short* Ps = Vt + 32 * PVLD;      // 4*16*264
    int tid = threadIdx.x, lane = tid & 63, w = tid >> 6;
    int tile = blockIdx.x, h = blockIdx.y, b = blockIdx.z;
    int lr = lane & 15, g = lane >> 4;

    #pragma unroll
    for (int p = 0; p < 8; ++p) {
        int l = p * 32 + (tid >> 3);
        int c4 = (tid & 7) * 4;
        const short* kvrow = xkv + ((size_t)(b * LL + l)) * 512 + h * CHDIM;
        ushort4 kk = *(const ushort4*)(kvrow + c4);
        *(ushort4*)&Ks[l * KSLD + c4] = kk;
        ushort4 vv = *(const ushort4*)(kvrow + 256 + c4);
        Vt[(c4 + 0) * PVLD + l] = vv.x;
        Vt[(c4 + 1) * PVLD + l] = vv.y;
        Vt[(c4 + 2) * PVLD + l] = vv.z;
        Vt[(c4 + 3) * PVLD + l] = vv.w;
    }
    __syncthreads();

    int qrow = b * NN + tile * 64 + w * 16 + lr;
    bf16x8 afr = *(const bf16x8*)(xq + (size_t)qrow * CC + h * CHDIM + g * 8);
    f32x4 s[16];
    #pragma unroll
    for (int t = 0; t < 16; ++t) {
        bf16x8 kb = *(const bf16x8*)&Ks[(t * 16 + lr) * KSLD + g * 8];
        s[t] = __builtin_amdgcn_mfma_f32_16x16x32_bf16(afr, kb, (f32x4){0.f,0.f,0.f,0.f}, 0, 0, 0);
    }
    float rs[4] = {0.f, 0.f, 0.f, 0.f};
    #pragma unroll
    for (int t = 0; t < 16; ++t)
        #pragma unroll
        for (int r = 0; r < 4; ++r) { float e = __expf(s[t][r]); s[t][r] = e; rs[r] += e; }
    #pragma unroll
    for (int off = 1; off < 16; off <<= 1)
        #pragma unroll
        for (int r = 0; r < 4; ++r) rs[r] += __shfl_xor(rs[r], off, 64);
    short* Pw = Ps + w * 16 * PVLD;
    #pragma unroll
    for (int t = 0; t < 16; ++t)
        #pragma unroll
        for (int r = 0; r < 4; ++r)
            Pw[(g * 4 + r) * PVLD + t * 16 + lr] = f2bf(s[t][r]);
    f32x4 oacc[2] = {};
    #pragma unroll
    for (int kc = 0; kc < 8; ++kc) {
        bf16x8 pa = *(const bf16x8*)&Pw[lr * PVLD + kc * 32 + g * 8];
        #pragma unroll
        for (int n = 0; n < 2; ++n) {
            bf16x8 vb = *(const bf16x8*)&Vt[(n * 16 + lr) * PVLD + kc * 32 + g * 8];
            oacc[n] = __builtin_amdgcn_mfma_f32_16x16x32_bf16(pa, vb, oacc[n], 0, 0, 0);
        }
    }
    float inv[4];
    #pragma unroll
    for (int r = 0; r < 4; ++r) inv[r] = 1.0f / rs[r];
    #pragma unroll
    for (int n = 0; n < 2; ++n)
        #pragma unroll
        for (int r = 0; r < 4; ++r) {
            int orow = b * NN + tile * 64 + w * 16 + g * 4 + r;
            o[(size_t)orow * CC + h * CHDIM + n * 16 + lr] = __float2bfloat16(oacc[n][r] * inv[r]);
        }
}

extern "C" void kernel_launch(void* const* d_in, const int* in_sizes, int n_in,
                              void* d_out, int out_size, void* d_ws, size_t ws_size,
                              hipStream_t stream) {
    const float* feat        = (const float*)d_in[0];
    const float* memory      = (const float*)d_in[1];
    const int*   member_idx  = (const int*)d_in[2];
    const int*   cluster_mask= (const int*)d_in[3];
    const int*   pe_idx      = (const int*)d_in[4];
    const float* pre_table   = (const float*)d_in[6];
    const float* Wq    = (const float*)d_in[7];
    const float* bq    = (const float*)d_in[8];
    const float* Wkv   = (const float*)d_in[9];
    const float* bkv   = (const float*)d_in[10];
    const float* blank_k = (const float*)d_in[11];
    const float* blank_v = (const float*)d_in[12];
    const float* Wpe   = (const float*)d_in[13];
    const float* bpe   = (const float*)d_in[14];
    const float* Wproj = (const float*)d_in[15];
    const float* bproj = (const float*)d_in[16];
    const float* g1    = (const float*)d_in[17];
    const float* be1   = (const float*)d_in[18];
    const float* g2    = (const float*)d_in[19];
    const float* be2   = (const float*)d_in[20];
    const float* xWq   = (const float*)d_in[21];
    const float* xbq   = (const float*)d_in[22];
    const float* xWk   = (const float*)d_in[23];
    const float* xbk   = (const float*)d_in[24];
    const float* xWv   = (const float*)d_in[25];
    const float* xbv   = (const float*)d_in[26];
    const float* xWo   = (const float*)d_in[27];
    const float* xbo   = (const float*)d_in[28];
    const float* xg    = (const float*)d_in[29];
    const float* xbe   = (const float*)d_in[30];
    const float* W1    = (const float*)d_in[31];
    const float* bf1   = (const float*)d_in[32];
    const float* W2    = (const float*)d_in[33];
    const float* bf2   = (const float*)d_in[34];
    float* out = (float*)d_out;
    float* ws  = (float*)d_ws;

    // workspace layout (float units)
    __hip_bfloat16* qBf   = (__hip_bfloat16*)ws;              // [8192][256] bf16
    __hip_bfloat16* xqBf  = (__hip_bfloat16*)ws;              // alias (q dead after cluster_attn)
    unsigned char*  kv8   = (unsigned char*)(ws + 1048576);   // [8192][512] fp8
    __hip_bfloat16* xkvBf = (__hip_bfloat16*)(ws + 2097152);  // [512][512] bf16
    __hip_bfloat16* hBf   = (__hip_bfloat16*)(ws + 2228224);  // [8192][512] bf16
    float* feat1F = ws + 4325376;                             // [8192][256] f32
    __hip_bfloat16* aBf   = (__hip_bfloat16*)(ws + 6422528);  // [8192][256] bf16
    __hip_bfloat16* oBf   = (__hip_bfloat16*)(ws + 7471104);  // [8192][256] bf16
    __hip_bfloat16* WqkvT = (__hip_bfloat16*)(ws + 8519680);  // [768][256]
    __hip_bfloat16* WprojT= (__hip_bfloat16*)(ws + 8617984);  // [256][256]
    __hip_bfloat16* xWqT  = (__hip_bfloat16*)(ws + 8650752);
    __hip_bfloat16* xWoT  = (__hip_bfloat16*)(ws + 8683520);
    __hip_bfloat16* xWkvT = (__hip_bfloat16*)(ws + 8716288);  // [512][256]
    __hip_bfloat16* W1T   = (__hip_bfloat16*)(ws + 8781824);  // [512][256]
    __hip_bfloat16* W2T   = (__hip_bfloat16*)(ws + 8847360);  // [256][512]
    __hip_bfloat16* memBf = (__hip_bfloat16*)(ws + 8912896);  // [512][256]
    float* pet   = ws + 8978432;                              // 80000
    float* bqkv  = ws + 9058432;                              // 768
    float* xbkv  = ws + 9059200;                              // 512
    float* xbqS  = ws + 9059712;                              // 256

    const float scale = 0.17677669529663689f; // 1/sqrt(32)

    // ---- prep (single launch) ----
    WtArgs wa;
    wa.d[0] = { Wq,    WqkvT,          256, 256, 0,   scale };
    wa.d[1] = { Wkv,   WqkvT + 65536,  256, 512, 64,  1.0f };
    wa.d[2] = { Wproj, WprojT,         256, 256, 192, 1.0f };
    wa.d[3] = { xWq,   xWqT,           256, 256, 256, scale };
    wa.d[4] = { xWk,   xWkvT,          256, 256, 320, 1.0f };
    wa.d[5] = { xWv,   xWkvT + 65536,  256, 256, 384, 1.0f };
    wa.d[6] = { xWo,   xWoT,           256, 256, 448, 1.0f };
    wa.d[7] = { W1,    W1T,            256, 512, 512, 1.0f };
    wa.d[8] = { W2,    W2T,            512, 256, 640, 1.0f };
    prep_all_kernel<<<768 + 831, 256, 0, stream>>>(wa, pre_table, Wpe, bpe, pet,
                                                   bq, bkv, xbk, xbv, xbq, scale,
                                                   bqkv, xbkv, xbqS, memory, memBf);

    // ---- block ----
    ln_kernel<<<ROWS / 4, 256, 0, stream>>>(feat, g1, be1, aBf);
    mfma_gemm_kernel<0,2><<<dim3(12, 64), 256, 0, stream>>>(aBf, WqkvT, bqkv, qBf, nullptr, ROWS, 768, 256, kv8);
    cluster_attn_kernel<<<ROWS, 512, 0, stream>>>(qBf, kv8, member_idx, cluster_mask, pe_idx, pet, blank_k, blank_v, oBf);
    mfma_gemm_kernel<0,0><<<dim3(4, 64), 256, 0, stream>>>(oBf, WprojT, bproj, feat1F, feat, ROWS, 256, 256, nullptr);
    ln_kernel<<<ROWS / 4, 256, 0, stream>>>(feat1F, xg, xbe, aBf);
    {
        GemmPair gp;
        gp.A1 = aBf;   gp.B1 = xWqT;  gp.bias1 = xbqS; gp.out1 = xqBf;
        gp.A2 = memBf; gp.B2 = xWkvT; gp.bias2 = xbkv; gp.out2 = xkvBf;
        dual_gemm_kernel<<<dim3(12, 64), 256, 0, stream>>>(gp);
    }
    {
        size_t xlds = (256 * KSLD + 32 * PVLD + 4 * 16 * PVLD) * sizeof(short);
        cross_attn_kernel<<<dim3(NN / 64, HH, BB), 256, xlds, stream>>>(xqBf, xkvBf, oBf);
    }
    mfma_gemm_kernel<0,0><<<dim3(4, 64), 256, 0, stream>>>(oBf, xWoT, xbo, out, feat1F, ROWS, 256, 256, nullptr);
    ln_kernel<<<ROWS / 4, 256, 0, stream>>>(out, g2, be2, aBf);
    mfma_gemm_kernel<1,1><<<dim3(8, 64), 256, 0, stream>>>(aBf, W1T, bf1, hBf, nullptr, ROWS, HIDD, 256, nullptr);
    mfma_gemm_kernel<0,0><<<dim3(4, 64), 256, 0, stream>>>(hBf, W2T, bf2, out, out, ROWS, 256, HIDD, nullptr);
}